// Round 3
// baseline (501.475 us; speedup 1.0000x reference)
//
#include <hip/hip_runtime.h>
#include <hip/hip_bf16.h>
#include <stdint.h>

// ---------- types & helpers ----------
using f32x4  = __attribute__((ext_vector_type(4))) float;
using bf16x8 = __attribute__((ext_vector_type(8))) short;
using u16x4  = __attribute__((ext_vector_type(4))) ushort;

#define MFMA16(a, b, c) __builtin_amdgcn_mfma_f32_16x16x32_bf16((a), (b), (c), 0, 0, 0)

__device__ __forceinline__ void gload_lds16(const void* g, void* l) {
    __builtin_amdgcn_global_load_lds(
        (const __attribute__((address_space(1))) void*)g,
        (__attribute__((address_space(3))) void*)l, 16, 0, 0);
}

__device__ __forceinline__ ushort f2bf(float f) {
    union { float f; uint32_t u; } v; v.f = f;
    uint32_t r = v.u + 0x7fffu + ((v.u >> 16) & 1u);
    return (ushort)(r >> 16);
}

__device__ __forceinline__ uint32_t pk_bf16(float a, float b) {
    __hip_bfloat162 h = __float22bfloat162_rn(float2{a, b});
    union { __hip_bfloat162 h; uint32_t u; } v; v.h = h; return v.u;
}

#define NEG_BIG (-1.0e30f)

// ---------- pack f32 -> bf16 ----------
__global__ void pack_bf16_k(const float* __restrict__ in, ushort* __restrict__ out, int n4) {
    const int i = blockIdx.x * blockDim.x + threadIdx.x;
    if (i >= n4) return;
    const f32x4 v = *(const f32x4*)(in + (size_t)i * 4);
    u16x4 o;
    o[0] = f2bf(v[0]); o[1] = f2bf(v[1]); o[2] = f2bf(v[2]); o[3] = f2bf(v[3]);
    *(u16x4*)(out + (size_t)i * 4) = o;
}

// ---------- weight transpose: f32 in [R][C] -> bf16 out [C][R] ----------
__global__ void transpose_k(const float* __restrict__ in, ushort* __restrict__ out,
                            int R, int C) {
    __shared__ ushort tile[32][33];
    const int c0 = blockIdx.x * 32, r0 = blockIdx.y * 32;
    const int tx = threadIdx.x, ty = threadIdx.y;
    for (int i = ty; i < 32; i += 8)
        tile[i][tx] = f2bf(in[(size_t)(r0 + i) * C + c0 + tx]);
    __syncthreads();
    for (int i = ty; i < 32; i += 8)
        out[(size_t)(c0 + i) * R + r0 + tx] = tile[tx][i];
}

// ---------- m97-structure GEMM: C[M,N] = A[M,K] @ BT[N,K]^T + bias ----------
// MODE 0: f32 out (proj GEMM -> d_out), row stride N
// MODE 1: QKV split: cols [0,2048) -> qk buffer bf16 (stride 2048),
//         cols [2048,3072) -> V transposed bf16 vt[bh][d][t]
template <int MODE>
__global__ __launch_bounds__(256, 2)
void gemm_bt(const ushort* __restrict__ A, const ushort* __restrict__ BT,
             const float* __restrict__ bias, float* __restrict__ outF,
             ushort* __restrict__ qk, ushort* __restrict__ vt,
             int M, int N, int K) {
    __shared__ __align__(16) ushort As[128 * 32];
    __shared__ __align__(16) ushort Bs[128 * 32];
    const int tid  = threadIdx.x;
    const int lane = tid & 63;
    const int wid  = tid >> 6;
    const int l15  = lane & 15, lg = lane >> 4;
    const int tile_m = blockIdx.x * 128;
    const int tile_n = blockIdx.y * 128;
    const int wm = (wid >> 1) * 64;
    const int wn = (wid & 1) * 64;

    const f32x4 fzero = {0.f, 0.f, 0.f, 0.f};
    f32x4 acc[4][4];
#pragma unroll
    for (int i = 0; i < 4; ++i)
#pragma unroll
        for (int j = 0; j < 4; ++j) acc[i][j] = fzero;

    const int c0 = tid & 3;
    const int r0 = tid >> 2;                 // 0..63
    const ushort* Arow0 = A  + (size_t)(tile_m + r0)      * K + c0 * 8;
    const ushort* Arow1 = A  + (size_t)(tile_m + 64 + r0) * K + c0 * 8;
    const ushort* Brow0 = BT + (size_t)(tile_n + r0)      * K + c0 * 8;
    const ushort* Brow1 = BT + (size_t)(tile_n + 64 + r0) * K + c0 * 8;
    const int ldsb0 = (wid * 64) * 16;
    const int ldsb1 = (256 + wid * 64) * 16;

    for (int k0 = 0; k0 < K; k0 += 32) {
        gload_lds16(Arow0 + k0, (char*)As + ldsb0);
        gload_lds16(Arow1 + k0, (char*)As + ldsb1);
        gload_lds16(Brow0 + k0, (char*)Bs + ldsb0);
        gload_lds16(Brow1 + k0, (char*)Bs + ldsb1);
        __syncthreads();

        bf16x8 af[4], bfv[4];
#pragma unroll
        for (int mf = 0; mf < 4; ++mf)
            af[mf] = *(const bf16x8*)&As[(wm + mf * 16 + l15) * 32 + lg * 8];
#pragma unroll
        for (int nf = 0; nf < 4; ++nf)
            bfv[nf] = *(const bf16x8*)&Bs[(wn + nf * 16 + l15) * 32 + lg * 8];
#pragma unroll
        for (int mf = 0; mf < 4; ++mf)
#pragma unroll
            for (int nf = 0; nf < 4; ++nf)
                acc[mf][nf] = MFMA16(af[mf], bfv[nf], acc[mf][nf]);
        __syncthreads();
    }

    // epilogue: C row = tile_m+wm+mf*16+(lg*4+i), col = tile_n+wn+nf*16+l15
#pragma unroll
    for (int nf = 0; nf < 4; ++nf) {
        const int col = tile_n + wn + nf * 16 + l15;
        const float bv = bias[col];
#pragma unroll
        for (int mf = 0; mf < 4; ++mf) {
#pragma unroll
            for (int i = 0; i < 4; ++i) {
                const int row = tile_m + wm + mf * 16 + lg * 4 + i;
                const float val = acc[mf][nf][i] + bv;
                if (MODE == 0) {
                    outF[(size_t)row * N + col] = val;
                } else {
                    if (col < 2048) {
                        qk[(size_t)row * 2048 + col] = f2bf(val);
                    } else {
                        const int vc = col - 2048;
                        const int bb = row >> 11, t = row & 2047;
                        vt[((size_t)(bb * 16 + (vc >> 6)) * 64 + (vc & 63)) * 2048 + t] = f2bf(val);
                    }
                }
            }
        }
    }
}

// ---------- causal flash attention, barrier-free ----------
// qk: [B*T][2048] bf16 (q cols 0..1023, k cols 1024..2047, head h at h*64)
// vt: [B*NH][64][2048] bf16 (V transposed)
// ao: [B*T][1024] bf16
// grid: (16, 64), block 256 = 4 waves x 32 q-rows (QBLK=128, KVBLK=64).
// K/V read directly from global (L2-resident: 256KB per bh) -> NO __syncthreads.
// Only LDS use: wave-private P buffer (XOR-swizzled, pad 80 elems/row).
__global__ void attn_fwd(const ushort* __restrict__ qk, const ushort* __restrict__ vt,
                         ushort* __restrict__ ao) {
    const int tid  = threadIdx.x;
    const int lane = tid & 63;
    const int w    = tid >> 6;
    const int l15  = lane & 15, lg = lane >> 4;
    const int bh = blockIdx.y;
    const int b = bh >> 4, h = bh & 15;
    const int qw = blockIdx.x * 128 + w * 32;     // this wave's first q row

    __shared__ __align__(16) ushort Ps[4][32 * 80];   // per-wave P [32 q][64 kv], pad 80
    char* psw = (char*)&Ps[w][0];
    const int pswz = (l15 & 7) << 4;                  // XOR swizzle (row&7)<<4; rows qh*16+l15

    // Q B-frags: lane holds Q[qw+qh*16+l15][dc*32+lg*8+j]
    const ushort* qrow = qk + ((size_t)(b * 2048 + qw + l15)) * 2048 + h * 64 + lg * 8;
    bf16x8 qf[2][2];
    qf[0][0] = *(const bf16x8*)(qrow);
    qf[0][1] = *(const bf16x8*)(qrow + 32);
    qf[1][0] = *(const bf16x8*)(qrow + 16 * 2048);
    qf[1][1] = *(const bf16x8*)(qrow + 16 * 2048 + 32);

    const f32x4 fzero = {0.f, 0.f, 0.f, 0.f};
    f32x4 o[2][4];
#pragma unroll
    for (int qh = 0; qh < 2; ++qh)
#pragma unroll
        for (int f = 0; f < 4; ++f) o[qh][f] = fzero;
    float mrun[2] = {NEG_BIG, NEG_BIG};
    float lrun[2] = {0.f, 0.f};
    const float sscale = 0.125f * 1.4426950408889634f;  // HD^-0.5 * log2(e)

    // K A-frag base: lane reads K[kv0+hh*16+l15][dc*32+lg*8..+7]
    const ushort* kbl = qk + (size_t)b * 2048 * 2048 + 1024 + h * 64 + (size_t)l15 * 2048 + lg * 8;
    // V B-frag base: lane reads V^T[d=f*16+l15][kv0+ks*32+lg*8..+7]
    const ushort* vbl = vt + (size_t)bh * 64 * 2048 + (size_t)l15 * 2048 + lg * 8;

    const int ntiles = (qw + 95) >> 6;
    for (int t = 0; t < ntiles; ++t) {
        const int kv0 = t * 64;
        const bool masktile = (kv0 + 63 > qw);   // wave-uniform

        // K fragments (reused across both q-halves)
        bf16x8 kf[4][2];
#pragma unroll
        for (int hh = 0; hh < 4; ++hh)
#pragma unroll
            for (int dc = 0; dc < 2; ++dc)
                kf[hh][dc] = *(const bf16x8*)(kbl + (size_t)(kv0 + hh * 16) * 2048 + dc * 32);

#pragma unroll
        for (int qh = 0; qh < 2; ++qh) {
            // S^T = K.Q : lane holds S^T[kv0+hh*16+lg*4+i][qw+qh*16+l15]
            f32x4 st[4] = {fzero, fzero, fzero, fzero};
#pragma unroll
            for (int hh = 0; hh < 4; ++hh)
#pragma unroll
                for (int dc = 0; dc < 2; ++dc)
                    st[hh] = MFMA16(kf[hh][dc], qf[qh][dc], st[hh]);

            float p[16];
#pragma unroll
            for (int hh = 0; hh < 4; ++hh)
#pragma unroll
                for (int i = 0; i < 4; ++i)
                    p[hh * 4 + i] = st[hh][i] * sscale;
            if (masktile) {
                const int qg = qw + qh * 16 + l15;
#pragma unroll
                for (int hh = 0; hh < 4; ++hh)
#pragma unroll
                    for (int i = 0; i < 4; ++i) {
                        const int kvg = kv0 + hh * 16 + lg * 4 + i;
                        if (kvg > qg) p[hh * 4 + i] = NEG_BIG;
                    }
            }

            // row max (row = l15; reduce the 16 locals then across lg groups)
            float mt = p[0];
#pragma unroll
            for (int j = 1; j < 16; ++j) mt = fmaxf(mt, p[j]);
            mt = fmaxf(mt, __shfl_xor(mt, 16));
            mt = fmaxf(mt, __shfl_xor(mt, 32));

            // exact defer-rescale: if max didn't grow, alpha == 1 exactly
            if (!__all(mt <= mrun[qh])) {
                const float mn = fmaxf(mrun[qh], mt);
                const float alpha = exp2f(mrun[qh] - mn);
                mrun[qh] = mn;
                float ar[4];
#pragma unroll
                for (int i = 0; i < 4; ++i) ar[i] = __shfl(alpha, lg * 4 + i);
#pragma unroll
                for (int f = 0; f < 4; ++f)
#pragma unroll
                    for (int i = 0; i < 4; ++i) o[qh][f][i] *= ar[i];
                lrun[qh] *= alpha;
            }

            // P = exp2(S - m), row-sum, pack to LDS
            float rs = 0.f;
#pragma unroll
            for (int j = 0; j < 16; ++j) { p[j] = exp2f(p[j] - mrun[qh]); rs += p[j]; }
            rs += __shfl_xor(rs, 16);
            rs += __shfl_xor(rs, 32);
            lrun[qh] += rs;

            const int prow = qh * 16 + l15;
#pragma unroll
            for (int hh = 0; hh < 4; ++hh) {
                uint2 pk;
                pk.x = pk_bf16(p[hh * 4 + 0], p[hh * 4 + 1]);
                pk.y = pk_bf16(p[hh * 4 + 2], p[hh * 4 + 3]);
                *(uint2*)(psw + ((prow * 160 + hh * 32 + lg * 8) ^ pswz)) = pk;
            }
        }

        // O += P.V (wave-private LDS; compiler inserts lgkmcnt, no barrier needed)
#pragma unroll
        for (int qh = 0; qh < 2; ++qh) {
            const int prow = qh * 16 + l15;
            bf16x8 pf[2];
#pragma unroll
            for (int ks = 0; ks < 2; ++ks)
                pf[ks] = *(const bf16x8*)(psw + ((prow * 160 + ks * 64 + lg * 16) ^ pswz));
#pragma unroll
            for (int f = 0; f < 4; ++f)
#pragma unroll
                for (int ks = 0; ks < 2; ++ks) {
                    const bf16x8 vf = *(const bf16x8*)(vbl + (size_t)(f * 16) * 2048 + kv0 + ks * 32);
                    o[qh][f] = MFMA16(pf[ks], vf, o[qh][f]);
                }
        }
    }

    // epilogue: divide by l and store
#pragma unroll
    for (int qh = 0; qh < 2; ++qh) {
        float lr[4];
#pragma unroll
        for (int i = 0; i < 4; ++i) lr[i] = __shfl(lrun[qh], lg * 4 + i);
#pragma unroll
        for (int f = 0; f < 4; ++f)
#pragma unroll
            for (int i = 0; i < 4; ++i) {
                const int row = qw + qh * 16 + lg * 4 + i;
                const int col = h * 64 + f * 16 + l15;
                ao[((size_t)(b * 2048 + row)) * 1024 + col] = f2bf(o[qh][f][i] / lr[i]);
            }
    }
}

// ---------- launch ----------
extern "C" void kernel_launch(void* const* d_in, const int* in_sizes, int n_in,
                              void* d_out, int out_size, void* d_ws, size_t ws_size,
                              hipStream_t stream) {
    const float* x      = (const float*)d_in[0];
    const float* w_attn = (const float*)d_in[1];
    const float* b_attn = (const float*)d_in[2];
    const float* w_proj = (const float*)d_in[3];
    const float* b_proj = (const float*)d_in[4];
    float* out = (float*)d_out;

    ushort* ws  = (ushort*)d_ws;
    ushort* xb  = ws;                                   // 8192*1024
    ushort* wTa = xb  + (size_t)8192 * 1024;            // 3072*1024
    ushort* wTp = wTa + (size_t)3072 * 1024;            // 1024*1024
    ushort* qkb = wTp + (size_t)1024 * 1024;            // 8192*2048
    ushort* vtb = qkb + (size_t)8192 * 2048;            // 64*64*2048
    ushort* aob = vtb + (size_t)64 * 64 * 2048;         // 8192*1024
    const size_t needed = ((size_t)8192 * 1024 + (size_t)3072 * 1024 + (size_t)1024 * 1024 +
                           (size_t)8192 * 2048 + (size_t)64 * 64 * 2048 + (size_t)8192 * 1024) * 2;
    if (ws_size < needed) return;  // ws too small -> clean fail (absmax = max|ref|)

    // pack x to bf16
    pack_bf16_k<<<8192, 256, 0, stream>>>(x, xb, 8192 * 1024 / 4);
    // weight transposes (f32 -> bf16)
    transpose_k<<<dim3(96, 32), dim3(32, 8), 0, stream>>>(w_attn, wTa, 1024, 3072);
    transpose_k<<<dim3(32, 32), dim3(32, 8), 0, stream>>>(w_proj, wTp, 1024, 1024);
    // QKV projection (epilogue splits q/k and transposed V)
    gemm_bt<1><<<dim3(64, 24), 256, 0, stream>>>(xb, wTa, b_attn, nullptr, qkb, vtb, 8192, 3072, 1024);
    // causal flash attention (barrier-free)
    attn_fwd<<<dim3(16, 64), 256, 0, stream>>>(qkb, vtb, aob);
    // output projection -> f32 out
    gemm_bt<0><<<dim3(64, 8), 256, 0, stream>>>(aob, wTp, b_proj, out, nullptr, nullptr, 8192, 1024, 1024);
}

// Round 4
// 323.103 us; speedup vs baseline: 1.5521x; 1.5521x over previous
//
#include <hip/hip_runtime.h>
#include <hip/hip_bf16.h>
#include <stdint.h>

// ---------- types & helpers ----------
using f32x4  = __attribute__((ext_vector_type(4))) float;
using bf16x8 = __attribute__((ext_vector_type(8))) short;
using u16x4  = __attribute__((ext_vector_type(4))) ushort;

#define MFMA16(a, b, c) __builtin_amdgcn_mfma_f32_16x16x32_bf16((a), (b), (c), 0, 0, 0)

__device__ __forceinline__ void gload_lds16(const void* g, void* l) {
    __builtin_amdgcn_global_load_lds(
        (const __attribute__((address_space(1))) void*)g,
        (__attribute__((address_space(3))) void*)l, 16, 0, 0);
}

__device__ __forceinline__ ushort f2bf(float f) {
    union { float f; uint32_t u; } v; v.f = f;
    uint32_t r = v.u + 0x7fffu + ((v.u >> 16) & 1u);
    return (ushort)(r >> 16);
}
__device__ __forceinline__ float bf2f(ushort u) {
    union { uint32_t u; float f; } v; v.u = ((uint32_t)u) << 16;
    return v.f;
}
__device__ __forceinline__ uint32_t pk_bf16(float a, float b) {
    __hip_bfloat162 h = __float22bfloat162_rn(float2{a, b});
    union { __hip_bfloat162 h; uint32_t u; } v; v.h = h; return v.u;
}
__device__ __forceinline__ bf16x8 scale8(bf16x8 v, float s) {
    bf16x8 r;
#pragma unroll
    for (int j = 0; j < 8; ++j) r[j] = (short)f2bf(bf2f((ushort)v[j]) * s);
    return r;
}

#define NEG_BIG (-1.0e30f)

// ---------- pack f32 -> bf16 ----------
__global__ void pack_bf16_k(const float* __restrict__ in, ushort* __restrict__ out, int n4) {
    const int i = blockIdx.x * blockDim.x + threadIdx.x;
    if (i >= n4) return;
    const f32x4 v = *(const f32x4*)(in + (size_t)i * 4);
    u16x4 o;
    o[0] = f2bf(v[0]); o[1] = f2bf(v[1]); o[2] = f2bf(v[2]); o[3] = f2bf(v[3]);
    *(u16x4*)(out + (size_t)i * 4) = o;
}

// ---------- weight transpose: f32 in [R][C] -> bf16 out [C][R] ----------
__global__ void transpose_k(const float* __restrict__ in, ushort* __restrict__ out,
                            int R, int C) {
    __shared__ ushort tile[32][33];
    const int c0 = blockIdx.x * 32, r0 = blockIdx.y * 32;
    const int tx = threadIdx.x, ty = threadIdx.y;
    for (int i = ty; i < 32; i += 8)
        tile[i][tx] = f2bf(in[(size_t)(r0 + i) * C + c0 + tx]);
    __syncthreads();
    for (int i = ty; i < 32; i += 8)
        out[(size_t)(c0 + i) * R + r0 + tx] = tile[tx][i];
}

// ---------- m97-structure GEMM: C[M,N] = A[M,K] @ BT[N,K]^T + bias ----------
template <int MODE>
__global__ __launch_bounds__(256, 2)
void gemm_bt(const ushort* __restrict__ A, const ushort* __restrict__ BT,
             const float* __restrict__ bias, float* __restrict__ outF,
             ushort* __restrict__ qk, ushort* __restrict__ vt,
             int M, int N, int K) {
    __shared__ __align__(16) ushort As[128 * 32];
    __shared__ __align__(16) ushort Bs[128 * 32];
    const int tid  = threadIdx.x;
    const int lane = tid & 63;
    const int wid  = tid >> 6;
    const int l15  = lane & 15, lg = lane >> 4;
    const int tile_m = blockIdx.x * 128;
    const int tile_n = blockIdx.y * 128;
    const int wm = (wid >> 1) * 64;
    const int wn = (wid & 1) * 64;

    const f32x4 fzero = {0.f, 0.f, 0.f, 0.f};
    f32x4 acc[4][4];
#pragma unroll
    for (int i = 0; i < 4; ++i)
#pragma unroll
        for (int j = 0; j < 4; ++j) acc[i][j] = fzero;

    const int c0 = tid & 3;
    const int r0 = tid >> 2;
    const ushort* Arow0 = A  + (size_t)(tile_m + r0)      * K + c0 * 8;
    const ushort* Arow1 = A  + (size_t)(tile_m + 64 + r0) * K + c0 * 8;
    const ushort* Brow0 = BT + (size_t)(tile_n + r0)      * K + c0 * 8;
    const ushort* Brow1 = BT + (size_t)(tile_n + 64 + r0) * K + c0 * 8;
    const int ldsb0 = (wid * 64) * 16;
    const int ldsb1 = (256 + wid * 64) * 16;

    for (int k0 = 0; k0 < K; k0 += 32) {
        gload_lds16(Arow0 + k0, (char*)As + ldsb0);
        gload_lds16(Arow1 + k0, (char*)As + ldsb1);
        gload_lds16(Brow0 + k0, (char*)Bs + ldsb0);
        gload_lds16(Brow1 + k0, (char*)Bs + ldsb1);
        __syncthreads();

        bf16x8 af[4], bfv[4];
#pragma unroll
        for (int mf = 0; mf < 4; ++mf)
            af[mf] = *(const bf16x8*)&As[(wm + mf * 16 + l15) * 32 + lg * 8];
#pragma unroll
        for (int nf = 0; nf < 4; ++nf)
            bfv[nf] = *(const bf16x8*)&Bs[(wn + nf * 16 + l15) * 32 + lg * 8];
#pragma unroll
        for (int mf = 0; mf < 4; ++mf)
#pragma unroll
            for (int nf = 0; nf < 4; ++nf)
                acc[mf][nf] = MFMA16(af[mf], bfv[nf], acc[mf][nf]);
        __syncthreads();
    }

#pragma unroll
    for (int nf = 0; nf < 4; ++nf) {
        const int col = tile_n + wn + nf * 16 + l15;
        const float bv = bias[col];
#pragma unroll
        for (int mf = 0; mf < 4; ++mf) {
#pragma unroll
            for (int i = 0; i < 4; ++i) {
                const int row = tile_m + wm + mf * 16 + lg * 4 + i;
                const float val = acc[mf][nf][i] + bv;
                if (MODE == 0) {
                    outF[(size_t)row * N + col] = val;
                } else {
                    if (col < 2048) {
                        qk[(size_t)row * 2048 + col] = f2bf(val);
                    } else {
                        const int vc = col - 2048;
                        const int bb = row >> 11, t = row & 2047;
                        vt[((size_t)(bb * 16 + (vc >> 6)) * 64 + (vc & 63)) * 2048 + t] = f2bf(val);
                    }
                }
            }
        }
    }
}

// ---------- causal flash attention: staged + double-buffered + fold-balanced ----------
// qk: [B*T][2048] bf16 (q cols 0..1023, k cols 1024..2047, head h at h*64)
// vt: [B*NH][64][2048] bf16 (V transposed)
// ao: [B*T][1024] bf16
// grid (8, 64), block 256 = 4 waves x 32 q-rows (QBLK=128, KVBLK=64).
// Block bx handles q-tiles {bx, 15-bx}: uniform 34 kv-iterations per block.
__global__ __launch_bounds__(256)
void attn_fwd(const ushort* __restrict__ qk, const ushort* __restrict__ vt,
              ushort* __restrict__ ao) {
    const int tid  = threadIdx.x;
    const int lane = tid & 63;
    const int w    = tid >> 6;
    const int l15  = lane & 15, lg = lane >> 4;
    const int bh = blockIdx.y;
    const int b = bh >> 4, h = bh & 15;

    __shared__ __align__(16) ushort Ks[2][64 * 64];   // [kv][d], chunk-swizzled
    __shared__ __align__(16) ushort Vs[2][64 * 64];   // [d][kv], chunk-swizzled
    __shared__ __align__(16) ushort Ps[4][32 * 80];   // per-wave P [32 q][64 kv], pad 80

    char* psw = (char*)&Ps[w][0];
    const int pswz = (l15 & 7) << 4;

    const ushort* kbase = qk + (size_t)b * 2048 * 2048 + 1024 + h * 64;
    const ushort* vbase = vt + (size_t)bh * 64 * 2048;
    const float sscale = 0.125f * 1.4426950408889634f;   // HD^-0.5 * log2(e)

    // staging coords: 512 chunks (64 rows x 8), 2 issues of 256; src chunk = c ^ (row&7)
    const int srow0 = tid >> 3,        schk0 = (tid & 7) ^ (srow0 & 7);
    const int srow1 = (256 + tid) >> 3, schk1 = (tid & 7) ^ (srow1 & 7);

    for (int pass = 0; pass < 2; ++pass) {
        const int q0 = (pass ? (15 - blockIdx.x) : blockIdx.x) * 128;
        const int qw = q0 + w * 32;

        // Q B-frags, pre-scaled by sscale: lane holds Q[qw+qh*16+l15][dc*32+lg*8+j]
        const ushort* qrow = qk + ((size_t)(b * 2048 + qw + l15)) * 2048 + h * 64 + lg * 8;
        bf16x8 qf[2][2];
        qf[0][0] = scale8(*(const bf16x8*)(qrow), sscale);
        qf[0][1] = scale8(*(const bf16x8*)(qrow + 32), sscale);
        qf[1][0] = scale8(*(const bf16x8*)(qrow + 16 * 2048), sscale);
        qf[1][1] = scale8(*(const bf16x8*)(qrow + 16 * 2048 + 32), sscale);

        const f32x4 fzero = {0.f, 0.f, 0.f, 0.f};
        f32x4 o[2][4];
#pragma unroll
        for (int qh = 0; qh < 2; ++qh)
#pragma unroll
            for (int f = 0; f < 4; ++f) o[qh][f] = fzero;
        float mrun[2] = {NEG_BIG, NEG_BIG};
        float lrun[2] = {0.f, 0.f};

        const int nt = q0 / 64 + 2;

        // prologue: stage tile 0 into buf 0
        {
            gload_lds16(kbase + (size_t)srow0 * 2048 + schk0 * 8, (char*)Ks[0] + tid * 16);
            gload_lds16(kbase + (size_t)srow1 * 2048 + schk1 * 8, (char*)Ks[0] + (256 + tid) * 16);
            gload_lds16(vbase + (size_t)srow0 * 2048 + schk0 * 8, (char*)Vs[0] + tid * 16);
            gload_lds16(vbase + (size_t)srow1 * 2048 + schk1 * 8, (char*)Vs[0] + (256 + tid) * 16);
        }
        __syncthreads();

        for (int t = 0; t < nt; ++t) {
            const int cur = t & 1;
            const int kv0 = t * 64;
            // stage next tile into the other buffer (overlaps with compute below)
            if (t + 1 < nt) {
                const int nkv = kv0 + 64;
                ushort* kd = Ks[cur ^ 1];
                ushort* vd = Vs[cur ^ 1];
                gload_lds16(kbase + (size_t)(nkv + srow0) * 2048 + schk0 * 8, (char*)kd + tid * 16);
                gload_lds16(kbase + (size_t)(nkv + srow1) * 2048 + schk1 * 8, (char*)kd + (256 + tid) * 16);
                gload_lds16(vbase + (size_t)srow0 * 2048 + nkv + schk0 * 8, (char*)vd + tid * 16);
                gload_lds16(vbase + (size_t)srow1 * 2048 + nkv + schk1 * 8, (char*)vd + (256 + tid) * 16);
            }

            if (kv0 <= qw + 31) {   // wave-uniform: this wave has live rows in this tile
                const char* kls = (const char*)Ks[cur];
                const char* vls = (const char*)Vs[cur];

                // K A-frags: K[kv0+hh*16+l15][dc*32+lg*8..], physical chunk = (dc*4+lg)^(l15&7)
                bf16x8 kf[4][2];
#pragma unroll
                for (int hh = 0; hh < 4; ++hh)
#pragma unroll
                    for (int dc = 0; dc < 2; ++dc)
                        kf[hh][dc] = *(const bf16x8*)(kls + (hh * 16 + l15) * 128 +
                                                      (((dc * 4 + lg) ^ (l15 & 7)) << 4));

#pragma unroll
                for (int qh = 0; qh < 2; ++qh) {
                    if (kv0 > qw + qh * 16 + 15) continue;   // wave-uniform half-skip
                    // S^T = K.Q : lane holds S^T[kv0+hh*16+lg*4+i][qw+qh*16+l15]
                    f32x4 st[4] = {fzero, fzero, fzero, fzero};
#pragma unroll
                    for (int hh = 0; hh < 4; ++hh)
#pragma unroll
                        for (int dc = 0; dc < 2; ++dc)
                            st[hh] = MFMA16(kf[hh][dc], qf[qh][dc], st[hh]);

                    float p[16];
#pragma unroll
                    for (int hh = 0; hh < 4; ++hh)
#pragma unroll
                        for (int i = 0; i < 4; ++i) p[hh * 4 + i] = st[hh][i];
                    if (kv0 + 63 > qw + qh * 16) {           // diagonal tile for this half
                        const int qg = qw + qh * 16 + l15;
#pragma unroll
                        for (int hh = 0; hh < 4; ++hh)
#pragma unroll
                            for (int i = 0; i < 4; ++i) {
                                const int kvg = kv0 + hh * 16 + lg * 4 + i;
                                if (kvg > qg) p[hh * 4 + i] = NEG_BIG;
                            }
                    }

                    float mt = p[0];
#pragma unroll
                    for (int j = 1; j < 16; ++j) mt = fmaxf(mt, p[j]);
                    mt = fmaxf(mt, __shfl_xor(mt, 16));
                    mt = fmaxf(mt, __shfl_xor(mt, 32));

                    if (!__all(mt <= mrun[qh])) {            // exact defer-rescale
                        const float mn = fmaxf(mrun[qh], mt);
                        const float alpha = exp2f(mrun[qh] - mn);
                        mrun[qh] = mn;
                        float ar[4];
#pragma unroll
                        for (int i = 0; i < 4; ++i) ar[i] = __shfl(alpha, lg * 4 + i);
#pragma unroll
                        for (int f = 0; f < 4; ++f)
#pragma unroll
                            for (int i = 0; i < 4; ++i) o[qh][f][i] *= ar[i];
                        lrun[qh] *= alpha;
                    }

                    float rs = 0.f;
#pragma unroll
                    for (int j = 0; j < 16; ++j) { p[j] = exp2f(p[j] - mrun[qh]); rs += p[j]; }
                    rs += __shfl_xor(rs, 16);
                    rs += __shfl_xor(rs, 32);
                    lrun[qh] += rs;

                    const int prow = qh * 16 + l15;
#pragma unroll
                    for (int hh = 0; hh < 4; ++hh) {
                        uint2 pk;
                        pk.x = pk_bf16(p[hh * 4 + 0], p[hh * 4 + 1]);
                        pk.y = pk_bf16(p[hh * 4 + 2], p[hh * 4 + 3]);
                        *(uint2*)(psw + ((prow * 160 + hh * 32 + lg * 8) ^ pswz)) = pk;
                    }
                }

                // P A-frags for both halves: P[q=prow][kv = ks*32+lg*8..]
                bf16x8 pf[2][2];
#pragma unroll
                for (int qh = 0; qh < 2; ++qh)
#pragma unroll
                    for (int ks = 0; ks < 2; ++ks)
                        pf[qh][ks] = *(const bf16x8*)(psw + (((qh * 16 + l15) * 160 + ks * 64 + lg * 16) ^ pswz));

                // O += P.V ; V B-frags shared across q-halves (f-outer)
#pragma unroll
                for (int f = 0; f < 4; ++f) {
                    const int vrow = f * 16 + l15;
                    bf16x8 vf0 = *(const bf16x8*)(vls + vrow * 128 + ((lg ^ (l15 & 7)) << 4));
                    bf16x8 vf1 = *(const bf16x8*)(vls + vrow * 128 + (((4 + lg) ^ (l15 & 7)) << 4));
#pragma unroll
                    for (int qh = 0; qh < 2; ++qh) {
                        if (kv0 > qw + qh * 16 + 15) continue;
                        o[qh][f] = MFMA16(pf[qh][0], vf0, o[qh][f]);
                        o[qh][f] = MFMA16(pf[qh][1], vf1, o[qh][f]);
                    }
                }
            }
            __syncthreads();   // staged buf ready + all waves done with cur buf
        }

        // epilogue: divide by l and store
#pragma unroll
        for (int qh = 0; qh < 2; ++qh) {
            float lr[4];
#pragma unroll
            for (int i = 0; i < 4; ++i) lr[i] = __shfl(lrun[qh], lg * 4 + i);
#pragma unroll
            for (int f = 0; f < 4; ++f)
#pragma unroll
                for (int i = 0; i < 4; ++i) {
                    const int row = qw + qh * 16 + lg * 4 + i;
                    const int col = h * 64 + f * 16 + l15;
                    ao[((size_t)(b * 2048 + row)) * 1024 + col] = f2bf(o[qh][f][i] / lr[i]);
                }
        }
    }
}

// ---------- launch ----------
extern "C" void kernel_launch(void* const* d_in, const int* in_sizes, int n_in,
                              void* d_out, int out_size, void* d_ws, size_t ws_size,
                              hipStream_t stream) {
    const float* x      = (const float*)d_in[0];
    const float* w_attn = (const float*)d_in[1];
    const float* b_attn = (const float*)d_in[2];
    const float* w_proj = (const float*)d_in[3];
    const float* b_proj = (const float*)d_in[4];
    float* out = (float*)d_out;

    ushort* ws  = (ushort*)d_ws;
    ushort* xb  = ws;                                   // 8192*1024
    ushort* wTa = xb  + (size_t)8192 * 1024;            // 3072*1024
    ushort* wTp = wTa + (size_t)3072 * 1024;            // 1024*1024
    ushort* qkb = wTp + (size_t)1024 * 1024;            // 8192*2048
    ushort* vtb = qkb + (size_t)8192 * 2048;            // 64*64*2048
    ushort* aob = vtb + (size_t)64 * 64 * 2048;         // 8192*1024
    const size_t needed = ((size_t)8192 * 1024 + (size_t)3072 * 1024 + (size_t)1024 * 1024 +
                           (size_t)8192 * 2048 + (size_t)64 * 64 * 2048 + (size_t)8192 * 1024) * 2;
    if (ws_size < needed) return;

    pack_bf16_k<<<8192, 256, 0, stream>>>(x, xb, 8192 * 1024 / 4);
    transpose_k<<<dim3(96, 32), dim3(32, 8), 0, stream>>>(w_attn, wTa, 1024, 3072);
    transpose_k<<<dim3(32, 32), dim3(32, 8), 0, stream>>>(w_proj, wTp, 1024, 1024);
    gemm_bt<1><<<dim3(64, 24), 256, 0, stream>>>(xb, wTa, b_attn, nullptr, qkb, vtb, 8192, 3072, 1024);
    attn_fwd<<<dim3(8, 64), 256, 0, stream>>>(qkb, vtb, aob);
    gemm_bt<0><<<dim3(64, 8), 256, 0, stream>>>(aob, wTp, b_proj, out, nullptr, nullptr, 8192, 1024, 1024);
}